// Round 9
// baseline (11256.877 us; speedup 1.0000x reference)
//
#include <hip/hip_runtime.h>
#include <stdint.h>

#define NBATCH 32
#define NPTS   65536
#define MCENT  2048
#define BPB    8                 // blocks per batch
#define THREADS 1024
#define CHUNK  (NPTS / BPB)      // 8192 points per block
#define WPT    (CHUNK / THREADS) // 8 points per thread
#define SLOT_ULL 8               // 64B-padded slot; words 0..3 = val,x,y,z

static __device__ __forceinline__ float f_from_bits(uint32_t u) {
    union { uint32_t u; float f; } c; c.u = u; return c.f;
}
static __device__ __forceinline__ uint32_t bits_from_f(float f) {
    union { float f; uint32_t u; } c; c.f = f; return c.u;
}
// tagged word: [63:32]=payload bits, [31:16]=iteration k, [15:0]=local idx
static __device__ __forceinline__ unsigned long long packw(uint32_t hi, int k, int pi) {
    return ((unsigned long long)hi << 32) | ((unsigned)k << 16) | (unsigned)pi;
}

// d_ws slots: [2 parities][NBATCH][BPB] x 64B. Each of the 4 used words is
// independently tagged with k: publishes are 4 parallel relaxed stores and a
// reader accepts a word only when its tag matches. Poison 0xAA../zero tags
// never match k in [1,2047] -> no init pass. Parity reuse is race-free: a
// block overwrites parity p at k+2 only after seeing all k+1 tags, which
// requires all peers to have banked their k-round reads.

__global__ __launch_bounds__(THREADS, 1) void fps_kernel(
    const float* __restrict__ xyz,      // [NBATCH, NPTS, 3] fp32
    float* __restrict__ out,            // [NBATCH, MCENT, 3] fp32
    unsigned long long* __restrict__ slots)
{
    const int t = threadIdx.x;
    // XCD-colocation swizzle: round-robin dispatch puts blockIdx%8 on XCD
    // (heuristic). b = idx&31, j = idx>>5 puts all 8 peers of batch b on
    // XCD b%8 (4 batches per XCD; 4x786KB xyz fits the 4MB L2).
    const int b = blockIdx.x & 31;   // batch
    const int j = blockIdx.x >> 5;   // block-within-batch
    const float* base = xyz + (size_t)b * NPTS * 3;
    const int p0 = j * CHUNK;

    // coords + running min-dist live in registers
    float x[WPT], y[WPT], z[WPT], d[WPT];
#pragma unroll
    for (int w = 0; w < WPT; ++w) {
        const int p = p0 + w * THREADS + t;
        x[w] = base[(size_t)p * 3 + 0];
        y[w] = base[(size_t)p * 3 + 1];
        z[w] = base[(size_t)p * 3 + 2];
        d[w] = 1e10f;
    }

    __shared__ float ldsC[4];     // broadcast center
    __shared__ float wv[16];      // per-wave partial max value
    __shared__ int   wi[16];      // per-wave partial argmax (local idx)
    __shared__ float wx[16], wy[16], wz[16];  // candidate coords

    if (t == 0) {
        const float cx = base[0], cy = base[1], cz = base[2];
        ldsC[0] = cx; ldsC[1] = cy; ldsC[2] = cz;
        if (j == 0) {
            float* o = out + (size_t)b * MCENT * 3;
            o[0] = cx; o[1] = cy; o[2] = cz;
        }
    }

    const int wave = t >> 6;
    const int lane = t & 63;

    for (int k = 1; k < MCENT; ++k) {
        __syncthreads();                         // ldsC = c_{k-1} valid
        const float cx = ldsC[0], cy = ldsC[1], cz = ldsC[2];

        // deferred output write: row k-1 = c_{k-1}, by wave1 lane0 of block 0.
        // Store drains during the exchange window -> off the critical path.
        if (j == 0 && t == 64) {
            float* o = out + ((size_t)b * MCENT + (k - 1)) * 3;
            o[0] = cx; o[1] = cy; o[2] = cz;
        }

        float bv = -1.0f; int bp = 0;
        float bx = 0.0f, by = 0.0f, bz = 0.0f;
#pragma unroll
        for (int w = 0; w < WPT; ++w) {
            // bit-exact reference arithmetic (verified R7/R8): subs, then
            // fma(dz,dz, fma(dx,dx, mul(dy,dy)))
            const float dx = __fsub_rn(x[w], cx);
            const float dy = __fsub_rn(y[w], cy);
            const float dz = __fsub_rn(z[w], cz);
            const float s  = __fmaf_rn(dz, dz,
                             __fmaf_rn(dx, dx,
                             __fmul_rn(dy, dy)));
            const float nd = fminf(d[w], s);
            d[w] = nd;
            if (nd > bv) { bv = nd; bp = w * THREADS + t;
                           bx = x[w]; by = y[w]; bz = z[w]; }
        }

        // wave-level argmax (64 lanes), tie -> smaller index; carry coords
#pragma unroll
        for (int off = 32; off >= 1; off >>= 1) {
            const float ov = __shfl_down(bv, off);
            const int   oi = __shfl_down(bp, off);
            const float ox = __shfl_down(bx, off);
            const float oy = __shfl_down(by, off);
            const float oz = __shfl_down(bz, off);
            if (ov > bv || (ov == bv && oi < bp)) {
                bv = ov; bp = oi; bx = ox; by = oy; bz = oz;
            }
        }
        if (lane == 0) { wv[wave] = bv; wi[wave] = bp;
                         wx[wave] = bx; wy[wave] = by; wz[wave] = bz; }
        __syncthreads();

        if (wave == 0) {
            // cross-wave reduce on lanes 0..15 via shuffle (tie -> smaller idx)
            float pv; int pi; float px, py, pz;
            if (lane < 16) { pv = wv[lane]; pi = wi[lane];
                             px = wx[lane]; py = wy[lane]; pz = wz[lane]; }
            else           { pv = -1.0f; pi = 0x7fffffff;
                             px = 0.0f; py = 0.0f; pz = 0.0f; }
#pragma unroll
            for (int off = 8; off >= 1; off >>= 1) {
                const float ov = __shfl_down(pv, off);
                const int   oi = __shfl_down(pi, off);
                const float ox = __shfl_down(px, off);
                const float oy = __shfl_down(py, off);
                const float oz = __shfl_down(pz, off);
                if (ov > pv || (ov == pv && oi < pi)) {
                    pv = ov; pi = oi; px = ox; py = oy; pz = oz;
                }
            }

            if (lane == 0) {
                unsigned long long* sl =
                    slots + ((size_t)(k & 1) * (NBATCH * BPB) + (size_t)b * BPB) * SLOT_ULL;

                // publish: 4 independent tagged words, fire-and-forget
                __hip_atomic_store(&sl[j * SLOT_ULL + 0], packw(bits_from_f(pv), k, pi),
                                   __ATOMIC_RELAXED, __HIP_MEMORY_SCOPE_AGENT);
                __hip_atomic_store(&sl[j * SLOT_ULL + 1], packw(bits_from_f(px), k, pi),
                                   __ATOMIC_RELAXED, __HIP_MEMORY_SCOPE_AGENT);
                __hip_atomic_store(&sl[j * SLOT_ULL + 2], packw(bits_from_f(py), k, pi),
                                   __ATOMIC_RELAXED, __HIP_MEMORY_SCOPE_AGENT);
                __hip_atomic_store(&sl[j * SLOT_ULL + 3], packw(bits_from_f(pz), k, pi),
                                   __ATOMIC_RELAXED, __HIP_MEMORY_SCOPE_AGENT);

                // hot spin until all 4 words of all 8 peers carry tag k
                unsigned long long va[BPB], xa[BPB], ya[BPB], za[BPB];
                bool ok;
                do {
                    ok = true;
#pragma unroll
                    for (int jj = 0; jj < BPB; ++jj) {
                        va[jj] = __hip_atomic_load(&sl[jj * SLOT_ULL + 0],
                                                   __ATOMIC_RELAXED, __HIP_MEMORY_SCOPE_AGENT);
                        xa[jj] = __hip_atomic_load(&sl[jj * SLOT_ULL + 1],
                                                   __ATOMIC_RELAXED, __HIP_MEMORY_SCOPE_AGENT);
                        ya[jj] = __hip_atomic_load(&sl[jj * SLOT_ULL + 2],
                                                   __ATOMIC_RELAXED, __HIP_MEMORY_SCOPE_AGENT);
                        za[jj] = __hip_atomic_load(&sl[jj * SLOT_ULL + 3],
                                                   __ATOMIC_RELAXED, __HIP_MEMORY_SCOPE_AGENT);
                    }
#pragma unroll
                    for (int jj = 0; jj < BPB; ++jj) {
                        const uint32_t kk = (uint32_t)k;
                        ok &= (((uint32_t)va[jj]) >> 16) == kk;
                        ok &= (((uint32_t)xa[jj]) >> 16) == kk;
                        ok &= (((uint32_t)ya[jj]) >> 16) == kk;
                        ok &= (((uint32_t)za[jj]) >> 16) == kk;
                    }
                } while (!ok);

                // global winner; jj ascending + explicit idx -> first occurrence
                float gv = -1.0f; int gidx = 0;
                float gx = 0.0f, gy = 0.0f, gz = 0.0f;
#pragma unroll
                for (int jj = 0; jj < BPB; ++jj) {
                    const float v  = f_from_bits((uint32_t)(va[jj] >> 32));
                    const int   gi = jj * CHUNK + (int)(va[jj] & 0xffffull);
                    if (v > gv || (v == gv && gi < gidx)) {
                        gv = v; gidx = gi;
                        gx = f_from_bits((uint32_t)(xa[jj] >> 32));
                        gy = f_from_bits((uint32_t)(ya[jj] >> 32));
                        gz = f_from_bits((uint32_t)(za[jj] >> 32));
                    }
                }

                ldsC[0] = gx; ldsC[1] = gy; ldsC[2] = gz;
            }
        }
    }

    // flush last output row (c_{MCENT-1} sits in ldsC)
    __syncthreads();
    if (j == 0 && t == 0) {
        float* o = out + ((size_t)b * MCENT + (MCENT - 1)) * 3;
        o[0] = ldsC[0]; o[1] = ldsC[1]; o[2] = ldsC[2];
    }
}

extern "C" void kernel_launch(void* const* d_in, const int* in_sizes, int n_in,
                              void* d_out, int out_size, void* d_ws, size_t ws_size,
                              hipStream_t stream) {
    const float* xyz = (const float*)d_in[0];
    float* out = (float*)d_out;
    unsigned long long* slots = (unsigned long long*)d_ws; // needs 32 KiB

    fps_kernel<<<dim3(NBATCH * BPB), dim3(THREADS), 0, stream>>>(xyz, out, slots);
}

// Round 10
// 8062.962 us; speedup vs baseline: 1.3961x; 1.3961x over previous
//
#include <hip/hip_runtime.h>
#include <stdint.h>

#define NBATCH 32
#define NPTS   65536
#define MCENT  2048
#define BPB    8                 // blocks per batch
#define THREADS 1024
#define CHUNK  (NPTS / BPB)      // 8192 points per block
#define WPT    (CHUNK / THREADS) // 8 points per thread
#define SLOT_ULL 4               // 32B per peer: words 0..3 = val,x,y,z

static __device__ __forceinline__ float f_from_bits(uint32_t u) {
    union { uint32_t u; float f; } c; c.u = u; return c.f;
}
static __device__ __forceinline__ uint32_t bits_from_f(float f) {
    union { float f; uint32_t u; } c; c.f = f; return c.u;
}
// tagged word: [63:32]=payload bits, [31:16]=iteration k, [15:0]=local idx
static __device__ __forceinline__ unsigned long long packw(uint32_t hi, int k, int pi) {
    return ((unsigned long long)hi << 32) | ((unsigned)k << 16) | (unsigned)pi;
}

// d_ws slots: [2 parities][NBATCH][BPB x 4 ull] = 256B per batch per parity
// (4 cache lines polled per spin round). Every word is independently tagged
// with k: publishes are 4 parallel relaxed agent-scope stores; a reader
// accepts a word only when its tag matches. Poison 0xAA../zero tags never
// match k in [1,2047] -> no init pass. Parity reuse is race-free: a block
// overwrites parity p at k+2 only after seeing all k+1 tags, which requires
// all peers to have banked their k-round reads in registers.

__global__ __launch_bounds__(THREADS, 1) void fps_kernel(
    const float* __restrict__ xyz,      // [NBATCH, NPTS, 3] fp32
    float* __restrict__ out,            // [NBATCH, MCENT, 3] fp32
    unsigned long long* __restrict__ slots)
{
    const int t = threadIdx.x;
    // R8 mapping (empirically best peer placement; R9's &31 swizzle was 1.75x worse)
    const int b = blockIdx.x >> 3;   // batch
    const int j = blockIdx.x & 7;    // block-within-batch
    const float* base = xyz + (size_t)b * NPTS * 3;
    const int p0 = j * CHUNK;

    // coords + running min-dist live in registers
    float x[WPT], y[WPT], z[WPT], d[WPT];
#pragma unroll
    for (int w = 0; w < WPT; ++w) {
        const int p = p0 + w * THREADS + t;
        x[w] = base[(size_t)p * 3 + 0];
        y[w] = base[(size_t)p * 3 + 1];
        z[w] = base[(size_t)p * 3 + 2];
        d[w] = 1e10f;
    }

    __shared__ float ldsC[4];     // broadcast center
    __shared__ float wv[16];      // per-wave partial max value
    __shared__ int   wi[16];      // per-wave partial argmax (local idx)
    __shared__ float wx[16], wy[16], wz[16];  // candidate coords

    if (t == 0) {
        const float cx = base[0], cy = base[1], cz = base[2];
        ldsC[0] = cx; ldsC[1] = cy; ldsC[2] = cz;
        if (j == 0) {
            float* o = out + (size_t)b * MCENT * 3;
            o[0] = cx; o[1] = cy; o[2] = cz;
        }
    }

    const int wave = t >> 6;
    const int lane = t & 63;

    for (int k = 1; k < MCENT; ++k) {
        __syncthreads();                         // ldsC = c_{k-1} valid
        const float cx = ldsC[0], cy = ldsC[1], cz = ldsC[2];

        // deferred output write: row k-1, by a non-critical wave of block 0;
        // the store drains during the exchange window
        if (j == 0 && t == 64) {
            float* o = out + ((size_t)b * MCENT + (k - 1)) * 3;
            o[0] = cx; o[1] = cy; o[2] = cz;
        }

        float bv = -1.0f; int bp = 0;
        float bx = 0.0f, by = 0.0f, bz = 0.0f;
#pragma unroll
        for (int w = 0; w < WPT; ++w) {
            // bit-exact reference arithmetic (verified R7/R8/R9): subs, then
            // fma(dz,dz, fma(dx,dx, mul(dy,dy)))
            const float dx = __fsub_rn(x[w], cx);
            const float dy = __fsub_rn(y[w], cy);
            const float dz = __fsub_rn(z[w], cz);
            const float s  = __fmaf_rn(dz, dz,
                             __fmaf_rn(dx, dx,
                             __fmul_rn(dy, dy)));
            const float nd = fminf(d[w], s);
            d[w] = nd;
            if (nd > bv) { bv = nd; bp = w * THREADS + t;
                           bx = x[w]; by = y[w]; bz = z[w]; }
        }

        // wave-level argmax (64 lanes), tie -> smaller index; carry coords
#pragma unroll
        for (int off = 32; off >= 1; off >>= 1) {
            const float ov = __shfl_down(bv, off);
            const int   oi = __shfl_down(bp, off);
            const float ox = __shfl_down(bx, off);
            const float oy = __shfl_down(by, off);
            const float oz = __shfl_down(bz, off);
            if (ov > bv || (ov == bv && oi < bp)) {
                bv = ov; bp = oi; bx = ox; by = oy; bz = oz;
            }
        }
        if (lane == 0) { wv[wave] = bv; wi[wave] = bp;
                         wx[wave] = bx; wy[wave] = by; wz[wave] = bz; }
        __syncthreads();

        if (wave == 0) {
            // cross-wave reduce on lanes 0..15 via shuffle (tie -> smaller idx)
            float pv; int pi; float px, py, pz;
            if (lane < 16) { pv = wv[lane]; pi = wi[lane];
                             px = wx[lane]; py = wy[lane]; pz = wz[lane]; }
            else           { pv = -1.0f; pi = 0x7fffffff;
                             px = 0.0f; py = 0.0f; pz = 0.0f; }
#pragma unroll
            for (int off = 8; off >= 1; off >>= 1) {
                const float ov = __shfl_down(pv, off);
                const int   oi = __shfl_down(pi, off);
                const float ox = __shfl_down(px, off);
                const float oy = __shfl_down(py, off);
                const float oz = __shfl_down(pz, off);
                if (ov > pv || (ov == pv && oi < pi)) {
                    pv = ov; pi = oi; px = ox; py = oy; pz = oz;
                }
            }

            if (lane == 0) {
                unsigned long long* sl =
                    slots + ((size_t)(k & 1) * NBATCH + (size_t)b) * (BPB * SLOT_ULL);

                // publish: 4 independent tagged words, fire-and-forget
                __hip_atomic_store(&sl[j * SLOT_ULL + 0], packw(bits_from_f(pv), k, pi),
                                   __ATOMIC_RELAXED, __HIP_MEMORY_SCOPE_AGENT);
                __hip_atomic_store(&sl[j * SLOT_ULL + 1], packw(bits_from_f(px), k, pi),
                                   __ATOMIC_RELAXED, __HIP_MEMORY_SCOPE_AGENT);
                __hip_atomic_store(&sl[j * SLOT_ULL + 2], packw(bits_from_f(py), k, pi),
                                   __ATOMIC_RELAXED, __HIP_MEMORY_SCOPE_AGENT);
                __hip_atomic_store(&sl[j * SLOT_ULL + 3], packw(bits_from_f(pz), k, pi),
                                   __ATOMIC_RELAXED, __HIP_MEMORY_SCOPE_AGENT);

                // hot spin until all 4 words of all 8 peers carry tag k
                unsigned long long va[BPB], xa[BPB], ya[BPB], za[BPB];
                bool ok;
                do {
                    ok = true;
#pragma unroll
                    for (int jj = 0; jj < BPB; ++jj) {
                        va[jj] = __hip_atomic_load(&sl[jj * SLOT_ULL + 0],
                                                   __ATOMIC_RELAXED, __HIP_MEMORY_SCOPE_AGENT);
                        xa[jj] = __hip_atomic_load(&sl[jj * SLOT_ULL + 1],
                                                   __ATOMIC_RELAXED, __HIP_MEMORY_SCOPE_AGENT);
                        ya[jj] = __hip_atomic_load(&sl[jj * SLOT_ULL + 2],
                                                   __ATOMIC_RELAXED, __HIP_MEMORY_SCOPE_AGENT);
                        za[jj] = __hip_atomic_load(&sl[jj * SLOT_ULL + 3],
                                                   __ATOMIC_RELAXED, __HIP_MEMORY_SCOPE_AGENT);
                    }
#pragma unroll
                    for (int jj = 0; jj < BPB; ++jj) {
                        const uint32_t kk = (uint32_t)k;
                        ok &= (((uint32_t)va[jj]) >> 16) == kk;
                        ok &= (((uint32_t)xa[jj]) >> 16) == kk;
                        ok &= (((uint32_t)ya[jj]) >> 16) == kk;
                        ok &= (((uint32_t)za[jj]) >> 16) == kk;
                    }
                } while (!ok);

                // global winner; jj ascending + explicit idx -> first occurrence
                float gv = -1.0f; int gidx = 0;
                float gx = 0.0f, gy = 0.0f, gz = 0.0f;
#pragma unroll
                for (int jj = 0; jj < BPB; ++jj) {
                    const float v  = f_from_bits((uint32_t)(va[jj] >> 32));
                    const int   gi = jj * CHUNK + (int)(va[jj] & 0xffffull);
                    if (v > gv || (v == gv && gi < gidx)) {
                        gv = v; gidx = gi;
                        gx = f_from_bits((uint32_t)(xa[jj] >> 32));
                        gy = f_from_bits((uint32_t)(ya[jj] >> 32));
                        gz = f_from_bits((uint32_t)(za[jj] >> 32));
                    }
                }

                ldsC[0] = gx; ldsC[1] = gy; ldsC[2] = gz;
            }
        }
    }

    // flush last output row (c_{MCENT-1} sits in ldsC)
    __syncthreads();
    if (j == 0 && t == 0) {
        float* o = out + ((size_t)b * MCENT + (MCENT - 1)) * 3;
        o[0] = ldsC[0]; o[1] = ldsC[1]; o[2] = ldsC[2];
    }
}

extern "C" void kernel_launch(void* const* d_in, const int* in_sizes, int n_in,
                              void* d_out, int out_size, void* d_ws, size_t ws_size,
                              hipStream_t stream) {
    const float* xyz = (const float*)d_in[0];
    float* out = (float*)d_out;
    unsigned long long* slots = (unsigned long long*)d_ws; // needs 16 KiB

    fps_kernel<<<dim3(NBATCH * BPB), dim3(THREADS), 0, stream>>>(xyz, out, slots);
}

// Round 11
// 7082.360 us; speedup vs baseline: 1.5894x; 1.1385x over previous
//
#include <hip/hip_runtime.h>
#include <stdint.h>

#define NBATCH 32
#define NPTS   65536
#define MCENT  2048
#define BPB    8                 // blocks per batch
#define THREADS 1024
#define CHUNK  (NPTS / BPB)      // 8192 points per block
#define WPT    (CHUNK / THREADS) // 8 points per thread
#define SLOT_ULL 8               // 64B per peer (exclusive cache line!); words 0..3 = val,x,y,z

static __device__ __forceinline__ float f_from_bits(uint32_t u) {
    union { uint32_t u; float f; } c; c.u = u; return c.f;
}
static __device__ __forceinline__ uint32_t bits_from_f(float f) {
    union { float f; uint32_t u; } c; c.f = f; return c.u;
}
// tagged word: [63:32]=payload bits, [31:16]=iteration k, [15:0]=local idx
static __device__ __forceinline__ unsigned long long packw(uint32_t hi, int k, int pi) {
    return ((unsigned long long)hi << 32) | ((unsigned)k << 16) | (unsigned)pi;
}

// d_ws slots: [2 parities][NBATCH][BPB] x 64B — one exclusive cache line per
// writer (R10's 32B packing shared lines between writers: +1.6ms regression).
// Every word independently tagged with k: publishes are 4 parallel relaxed
// agent-scope stores; a reader accepts a word only when its tag matches.
// Poison 0xAA../zero tags never match k in [1,2047] -> no init pass.
// Parity reuse race-free: a block overwrites parity p at k+2 only after
// seeing all k+1 tags, which requires all peers to have banked their k reads.

__global__ __launch_bounds__(THREADS, 1) void fps_kernel(
    const float* __restrict__ xyz,      // [NBATCH, NPTS, 3] fp32
    float* __restrict__ out,            // [NBATCH, MCENT, 3] fp32
    unsigned long long* __restrict__ slots)
{
    const int t = threadIdx.x;
    // R8 mapping (empirically best peer placement; R9's &31 swizzle was 1.75x worse)
    const int b = blockIdx.x >> 3;   // batch
    const int j = blockIdx.x & 7;    // block-within-batch
    const float* base = xyz + (size_t)b * NPTS * 3;
    const int p0 = j * CHUNK;

    // coords + running min-dist live in registers
    float x[WPT], y[WPT], z[WPT], d[WPT];
#pragma unroll
    for (int w = 0; w < WPT; ++w) {
        const int p = p0 + w * THREADS + t;
        x[w] = base[(size_t)p * 3 + 0];
        y[w] = base[(size_t)p * 3 + 1];
        z[w] = base[(size_t)p * 3 + 2];
        d[w] = 1e10f;
    }

    __shared__ float ldsC[4];     // broadcast center
    __shared__ float wv[16];      // per-wave partial max value
    __shared__ int   wi[16];      // per-wave partial argmax (local idx)
    __shared__ float wx[16], wy[16], wz[16];  // candidate coords

    if (t == 0) {
        const float cx = base[0], cy = base[1], cz = base[2];
        ldsC[0] = cx; ldsC[1] = cy; ldsC[2] = cz;
        if (j == 0) {
            float* o = out + (size_t)b * MCENT * 3;
            o[0] = cx; o[1] = cy; o[2] = cz;
        }
    }

    const int wave = t >> 6;
    const int lane = t & 63;

    for (int k = 1; k < MCENT; ++k) {
        __syncthreads();                         // ldsC = c_{k-1} valid
        const float cx = ldsC[0], cy = ldsC[1], cz = ldsC[2];

        // deferred output write: row k-1, by a non-critical wave of block 0;
        // the store drains during the exchange window
        if (j == 0 && t == 64) {
            float* o = out + ((size_t)b * MCENT + (k - 1)) * 3;
            o[0] = cx; o[1] = cy; o[2] = cz;
        }

        float bv = -1.0f; int bp = 0;
        float bx = 0.0f, by = 0.0f, bz = 0.0f;
#pragma unroll
        for (int w = 0; w < WPT; ++w) {
            // bit-exact reference arithmetic (verified R7-R10): subs, then
            // fma(dz,dz, fma(dx,dx, mul(dy,dy)))
            const float dx = __fsub_rn(x[w], cx);
            const float dy = __fsub_rn(y[w], cy);
            const float dz = __fsub_rn(z[w], cz);
            const float s  = __fmaf_rn(dz, dz,
                             __fmaf_rn(dx, dx,
                             __fmul_rn(dy, dy)));
            const float nd = fminf(d[w], s);
            d[w] = nd;
            if (nd > bv) { bv = nd; bp = w * THREADS + t;
                           bx = x[w]; by = y[w]; bz = z[w]; }
        }

        // wave-level argmax (64 lanes), tie -> smaller index; carry coords
#pragma unroll
        for (int off = 32; off >= 1; off >>= 1) {
            const float ov = __shfl_down(bv, off);
            const int   oi = __shfl_down(bp, off);
            const float ox = __shfl_down(bx, off);
            const float oy = __shfl_down(by, off);
            const float oz = __shfl_down(bz, off);
            if (ov > bv || (ov == bv && oi < bp)) {
                bv = ov; bp = oi; bx = ox; by = oy; bz = oz;
            }
        }
        if (lane == 0) { wv[wave] = bv; wi[wave] = bp;
                         wx[wave] = bx; wy[wave] = by; wz[wave] = bz; }
        __syncthreads();

        if (wave == 0) {
            // cross-wave reduce on lanes 0..15 via shuffle (tie -> smaller idx)
            float pv; int pi; float px, py, pz;
            if (lane < 16) { pv = wv[lane]; pi = wi[lane];
                             px = wx[lane]; py = wy[lane]; pz = wz[lane]; }
            else           { pv = -1.0f; pi = 0x7fffffff;
                             px = 0.0f; py = 0.0f; pz = 0.0f; }
#pragma unroll
            for (int off = 8; off >= 1; off >>= 1) {
                const float ov = __shfl_down(pv, off);
                const int   oi = __shfl_down(pi, off);
                const float ox = __shfl_down(px, off);
                const float oy = __shfl_down(py, off);
                const float oz = __shfl_down(pz, off);
                if (ov > pv || (ov == pv && oi < pi)) {
                    pv = ov; pi = oi; px = ox; py = oy; pz = oz;
                }
            }

            unsigned long long* sl =
                slots + ((size_t)(k & 1) * NBATCH + (size_t)b) * (BPB * SLOT_ULL);

            if (lane == 0) {
                // publish: 4 independent tagged words, fire-and-forget
                __hip_atomic_store(&sl[j * SLOT_ULL + 0], packw(bits_from_f(pv), k, pi),
                                   __ATOMIC_RELAXED, __HIP_MEMORY_SCOPE_AGENT);
                __hip_atomic_store(&sl[j * SLOT_ULL + 1], packw(bits_from_f(px), k, pi),
                                   __ATOMIC_RELAXED, __HIP_MEMORY_SCOPE_AGENT);
                __hip_atomic_store(&sl[j * SLOT_ULL + 2], packw(bits_from_f(py), k, pi),
                                   __ATOMIC_RELAXED, __HIP_MEMORY_SCOPE_AGENT);
                __hip_atomic_store(&sl[j * SLOT_ULL + 3], packw(bits_from_f(pz), k, pi),
                                   __ATOMIC_RELAXED, __HIP_MEMORY_SCOPE_AGENT);
            }

            // parallel poll: lane jj (0..7) owns peer jj's 4 words
            float rv = -1.0f, rx = 0.0f, ry = 0.0f, rz = 0.0f;
            int rgi = 0x7fffffff;
            if (lane < BPB) {
                unsigned long long w0, w1, w2, w3;
                bool ok;
                do {
                    w0 = __hip_atomic_load(&sl[lane * SLOT_ULL + 0],
                                           __ATOMIC_RELAXED, __HIP_MEMORY_SCOPE_AGENT);
                    w1 = __hip_atomic_load(&sl[lane * SLOT_ULL + 1],
                                           __ATOMIC_RELAXED, __HIP_MEMORY_SCOPE_AGENT);
                    w2 = __hip_atomic_load(&sl[lane * SLOT_ULL + 2],
                                           __ATOMIC_RELAXED, __HIP_MEMORY_SCOPE_AGENT);
                    w3 = __hip_atomic_load(&sl[lane * SLOT_ULL + 3],
                                           __ATOMIC_RELAXED, __HIP_MEMORY_SCOPE_AGENT);
                    const uint32_t kk = (uint32_t)k;
                    ok = (((uint32_t)w0 >> 16) == kk) & (((uint32_t)w1 >> 16) == kk) &
                         (((uint32_t)w2 >> 16) == kk) & (((uint32_t)w3 >> 16) == kk);
                } while (__ballot(ok) != 0xffull);   // all 8 active lanes ok

                rv  = f_from_bits((uint32_t)(w0 >> 32));
                rgi = lane * CHUNK + (int)(w0 & 0xffffull);
                rx  = f_from_bits((uint32_t)(w1 >> 32));
                ry  = f_from_bits((uint32_t)(w2 >> 32));
                rz  = f_from_bits((uint32_t)(w3 >> 32));
            }

            // winner across lanes 0..7 via shuffle; tie -> smaller global idx
#pragma unroll
            for (int off = 4; off >= 1; off >>= 1) {
                const float ov = __shfl_down(rv, off);
                const int   oi = __shfl_down(rgi, off);
                const float ox = __shfl_down(rx, off);
                const float oy = __shfl_down(ry, off);
                const float oz = __shfl_down(rz, off);
                if (ov > rv || (ov == rv && oi < rgi)) {
                    rv = ov; rgi = oi; rx = ox; ry = oy; rz = oz;
                }
            }

            if (lane == 0) { ldsC[0] = rx; ldsC[1] = ry; ldsC[2] = rz; }
        }
    }

    // flush last output row (c_{MCENT-1} sits in ldsC)
    __syncthreads();
    if (j == 0 && t == 0) {
        float* o = out + ((size_t)b * MCENT + (MCENT - 1)) * 3;
        o[0] = ldsC[0]; o[1] = ldsC[1]; o[2] = ldsC[2];
    }
}

extern "C" void kernel_launch(void* const* d_in, const int* in_sizes, int n_in,
                              void* d_out, int out_size, void* d_ws, size_t ws_size,
                              hipStream_t stream) {
    const float* xyz = (const float*)d_in[0];
    float* out = (float*)d_out;
    unsigned long long* slots = (unsigned long long*)d_ws; // needs 32 KiB

    fps_kernel<<<dim3(NBATCH * BPB), dim3(THREADS), 0, stream>>>(xyz, out, slots);
}